// Round 8
// baseline (253.486 us; speedup 1.0000x reference)
//
#include <hip/hip_runtime.h>
#include <hip/hip_bf16.h>

// AFT-Full on gfx950 — fragment-linear + MX-fp8 GEMM2 + XCD-slab scheduling.
// ew = exp(wbias) = 1 + E, |E|<=0.039: num = colsumZ + E@eKV, den = colsumK + E@eK.
// colsums exact (f32 atomics in GEMM1 epilogue); correction GEMM in fp8 e4m3 via
// mfma_scale_f32_32x32x64_f8f6f4 (scales pinned 1.0; static E*32, Z/4, /8 undo).
// Round-16: B (weights) moves to DIRECT global->VGPR loads (frag-linear => each
// B-frag is one coalesced 16B/lane global_load_dwordx4; per-XCD n-slab 512KB is
// L2-resident).  Five schedules all pinned at ~32% MfmaUtil because per-phase DS
// demand (64-128KB reads) exceeded MFMA demand — waves lgkm-stall on the shared
// DS pipe regardless of source order.  Now: DS = A-stage 8KB + A-reads 32KB per
// phase (~400cyc) < MFMA (512cyc); B rides the disjoint TA/L2 pipe (~570cyc),
// covered by one phase of vmcnt pipelining (B(g+1) loaded during phase g,
// compiler emits exact per-reg vmcnt).  A-frags keep a 1-phase register prefetch.
// LDS = A ring-4 x 8KB = 32KB (was 96-144KB) -> no LDS occupancy ceiling.
// FIFO audit (robust to in-phase reorder): end-of-g vmcnt(5) keeps exactly
// phase-g's 5 VMEM {4 Bld, 1 Ast}, draining Ast(g+2) before phase g+1 reads
// slot g+2; prologue vmcnt(0); tail 5 -> 4 -> none.

#define AS1(p) ((const __attribute__((address_space(1))) void*)(p))
#define AS3(p) ((__attribute__((address_space(3))) void*)(p))

typedef _Float16 half8 __attribute__((ext_vector_type(8)));
typedef _Float16 half4v __attribute__((ext_vector_type(4)));
typedef float floatx16 __attribute__((ext_vector_type(16)));
typedef int intx4 __attribute__((ext_vector_type(4)));
typedef int intx8 __attribute__((ext_vector_type(8)));

// f16 fragment-linear 128x64 tile (8192 halfs): [r>>5][k>>4][(k>>3)&1][r&31][k&7]
__device__ __forceinline__ long frag_off(int r, int k) {
  return (long)(((((r >> 5) * 4 + (k >> 4)) * 2 + ((k >> 3) & 1)) * 32 + (r & 31)) * 8 + (k & 7));
}
// fp8 fragment-linear 128x128 tile (16384 B)
__device__ __forceinline__ long off8(int r, int k) {
  return (long)((((((r >> 5) * 2 + ((k >> 6) & 1)) * 2 + ((k >> 4) & 1)) * 2 + ((k >> 5) & 1)) * 32 +
                 (r & 31)) * 16 + (k & 15));
}

// ---------------- prep_all ----------------
// blocks [0,1024): x -> f16 frag tiles; [1024,1536): W -> f16 tiles via LDS;
// [1536,1792): (exp(wbias)-1)*32 -> fp8 frag tiles
__global__ __launch_bounds__(256) void prep_all(
    const float* __restrict__ x, const float* __restrict__ wb, const float* __restrict__ Wq,
    const float* __restrict__ Wk, const float* __restrict__ Wv, const float* __restrict__ Wo,
    _Float16* __restrict__ x_h, char* __restrict__ E8, _Float16* __restrict__ WqkvT,
    _Float16* __restrict__ WoT) {
  __shared__ _Float16 lds[64 * 132];
  const int bid = blockIdx.x;
  const int tid = threadIdx.x;

  if (bid < 1024) {  // x -> f16 tiles
    const int tm = bid >> 4, tk = bid & 15;
    const long tbase = (long)bid * 8192;
#pragma unroll
    for (int p = 0; p < 4; ++p) {
      const int s = p * 256 + tid;
      const int r = ((s >> 8) << 5) + (s & 31);
      const int k = ((s >> 6) & 3) * 16 + ((s >> 5) & 1) * 8;
      const float* sp = x + (long)(tm * 128 + r) * 1024 + tk * 64 + k;
      const float4 v0 = *(const float4*)sp;
      const float4 v1 = *(const float4*)(sp + 4);
      half8 h;
      h[0] = (_Float16)v0.x; h[1] = (_Float16)v0.y; h[2] = (_Float16)v0.z; h[3] = (_Float16)v0.w;
      h[4] = (_Float16)v1.x; h[5] = (_Float16)v1.y; h[6] = (_Float16)v1.z; h[7] = (_Float16)v1.w;
      *(half8*)(x_h + tbase + (long)s * 8) = h;
    }
    return;
  }

  if (bid >= 1536) {  // E8: (exp(wb)-1)*32 -> fp8 frag tiles
    const int e = bid - 1536;
    const int tt = e >> 4, ts = e & 15;
    char* dst = E8 + (long)e * 16384;
#pragma unroll
    for (int p = 0; p < 16; ++p) {
      const int idx = p * 256 + tid;
      const int r = idx >> 5, k = (idx & 31) * 4;
      const float4 v = *(const float4*)(wb + (long)(tt * 128 + r) * 2048 + ts * 128 + k);
      const float e0 = (__expf(v.x) - 1.0f) * 32.0f, e1 = (__expf(v.y) - 1.0f) * 32.0f;
      const float e2 = (__expf(v.z) - 1.0f) * 32.0f, e3 = (__expf(v.w) - 1.0f) * 32.0f;
      int pk = __builtin_amdgcn_cvt_pk_fp8_f32(e0, e1, 0, false);
      pk = __builtin_amdgcn_cvt_pk_fp8_f32(e2, e3, pk, true);
      *(int*)(dst + off8(r, k)) = pk;
    }
    return;
  }

  // ---- weight tiler (f16) ----
  const int b2 = bid - 1024;
  const float* src0;
  const float* src1 = nullptr;
  _Float16* dst;
  int tn, tk, cb = 0;
  if (b2 < 128) {
    tn = b2 >> 4; tk = b2 & 15; src0 = Wq; dst = WqkvT;
  } else if (b2 < 384) {
    const int t = b2 - 128;
    tn = 8 + (t >> 4); tk = t & 15; cb = (tn - 8) * 64; src0 = Wk; src1 = Wv; dst = WqkvT;
  } else {
    const int t = b2 - 384;
    tn = t >> 4; tk = t & 15; src0 = Wo; dst = WoT;
  }
  if (!src1) {
#pragma unroll
    for (int p = 0; p < 8; ++p) {
      const int kl = p * 8 + (tid >> 5);
      const int cl = (tid & 31) * 4;
      const float4 v = *(const float4*)(src0 + (long)(tk * 64 + kl) * 1024 + tn * 128 + cl);
      half4v h;
      h[0] = (_Float16)v.x; h[1] = (_Float16)v.y; h[2] = (_Float16)v.z; h[3] = (_Float16)v.w;
      *(half4v*)(lds + kl * 132 + cl) = h;
    }
  } else {
#pragma unroll
    for (int m = 0; m < 2; ++m) {
      const float* s = m ? src1 : src0;
      const int rb = m ? 32 : 0;
#pragma unroll
      for (int p = 0; p < 4; ++p) {
        const int kl = p * 16 + (tid >> 4);
        const int cl = (tid & 15) * 4;
        const int rl = (cl >> 5) * 64 + rb + (cl & 31);
        const float4 v = *(const float4*)(s + (long)(tk * 64 + kl) * 1024 + cb + cl);
        half4v h;
        h[0] = (_Float16)v.x; h[1] = (_Float16)v.y; h[2] = (_Float16)v.z; h[3] = (_Float16)v.w;
        *(half4v*)(lds + kl * 132 + rl) = h;
      }
    }
  }
  __syncthreads();
  const long tbase = (long)(tn * 16 + tk) * 8192;
#pragma unroll
  for (int p = 0; p < 4; ++p) {
    const int s = p * 256 + tid;
    const int r = ((s >> 8) << 5) + (s & 31);
    const int kl = ((s >> 6) & 3) * 16 + ((s >> 5) & 1) * 8;
    half8 h;
#pragma unroll
    for (int j = 0; j < 8; ++j) h[j] = lds[(kl + j) * 132 + r];
    *(half8*)(dst + tbase + (long)s * 8) = h;
  }
}

// ---------------- f16 GEMM: 128x256, 8 waves, A-LDS ring-4 + B direct-to-reg ----------------
// K = 1024 = 32 K-halves of 32.  Phase g body:
//   {4 ds_read aNxt from slot (g+1)&3} {4 global_load bNxt = B(g+1) frags}
//   {gload_lds A-stage(g+3) -> slot (g+3)&3} {8 MFMA on aCur,bCur}
//   vmcnt(5) ; s_barrier.
// vmcnt(5) keeps exactly phase-g's 5 VMEM {4 Bld, 1 Ast} (robust to in-phase
// reorder), draining Ast(g+2) so phase g+1 may read slot g+2.  Compiler emits
// exact per-reg vmcnt for bCur before MFMA and lgkm for aCur.
template <int VM, bool STAGE, bool LDB, bool RDN, bool BAR>
__device__ __forceinline__ void aft_p(
    int g, const _Float16* __restrict__ Ablk, const _Float16* __restrict__ Bf0,
    const _Float16* __restrict__ Bf1, _Float16* ring, long thrA, int wid, int lane, int wm,
    half8 (&aCur)[2][2], half8 (&aNxt)[2][2], half8 (&bCur)[2][2], half8 (&bNxt)[2][2],
    floatx16 (&acc)[2][2]) {
  if (RDN) {
    const _Float16* sA = ring + ((g + 1) & 3) * 4096 + lane * 8;
#pragma unroll
    for (int mt = 0; mt < 2; ++mt)
#pragma unroll
      for (int ks = 0; ks < 2; ++ks)
        aNxt[mt][ks] = *(const half8*)(sA + (((wm >> 5) + mt) * 2 + ks) * 512);
  }
  if (LDB) {
    const long gb = (long)((g + 1) >> 1) * 8192 + (long)((g + 1) & 1) * 1024;
#pragma unroll
    for (int ks = 0; ks < 2; ++ks) {
      bNxt[0][ks] = *(const half8*)(Bf0 + gb + ks * 512);
      bNxt[1][ks] = *(const half8*)(Bf1 + gb + ks * 512);
    }
  }
  if (STAGE) {
    const int gs = g + 3;
    const long go = (long)(gs >> 1) * 8192 + (long)(gs & 1) * 1024 + thrA;
    __builtin_amdgcn_global_load_lds(AS1(Ablk + go), AS3(ring + (gs & 3) * 4096 + wid * 512), 16,
                                     0, 0);
  }
  __builtin_amdgcn_s_setprio(1);
#pragma unroll
  for (int ks = 0; ks < 2; ++ks)
#pragma unroll
    for (int mt = 0; mt < 2; ++mt)
#pragma unroll
      for (int nt = 0; nt < 2; ++nt)
        acc[mt][nt] =
            __builtin_amdgcn_mfma_f32_32x32x16_f16(aCur[mt][ks], bCur[nt][ks], acc[mt][nt], 0, 0, 0);
  __builtin_amdgcn_s_setprio(0);
  if (BAR) {
    asm volatile("s_waitcnt vmcnt(%0)" ::"i"(VM < 0 ? 0 : VM) : "memory");
    __builtin_amdgcn_s_barrier();
    asm volatile("" ::: "memory");
  }
}

// Block order: XCD x = f&7 owns m-slab [8x, 8x+8) of 128-row tiles, walks n slowly.
// MODE 0 (GEMM1): n0<1024 -> Qsig C-frag sigmoid(+bq); else K/V pair -> Zt8 + colsums.
// MODE 2 (GEMM3): fp32 row-major store + bias0.
template <int MODE>
__global__ __launch_bounds__(512, 2) void gemm_bt2(
    const _Float16* __restrict__ A, const _Float16* __restrict__ Bt, void* __restrict__ Cv,
    const float* __restrict__ bias0, const float* __restrict__ bias1,
    const float* __restrict__ bias2, char* __restrict__ Zt8, float* __restrict__ cs) {
  __shared__ __align__(16) _Float16 ring[16384];  // A ring: 4 x 4096 halfs = 32 KB
  const int tid = threadIdx.x;
  const int wid = tid >> 6, lane = tid & 63;
  const int l32 = lane & 31, khalf = lane >> 5;

  const int f = blockIdx.x;
  const int j = f >> 3;
  const int bxs = (f & 7) * 8 + (j & 7);
  const int bys = j >> 3;
  const int m0 = bxs * 128, n0 = bys * 256;
  const int wm = (wid >> 2) * 64, wn = (wid & 3) * 64;

  const _Float16* Ablk = A + (long)bxs * 131072;          // 16 tiles * 8192
  const _Float16* Bblk = Bt + (long)(bys * 2) * 131072;   // 2 consecutive 128-col tiles

  // B-frag global bases for this wave's two 32-col groups (frag-linear strides)
  const int c0 = wn, c1 = wn + 32;
  const _Float16* Bf0 = Bblk + (long)(c0 >> 7) * 131072 + ((c0 & 127) >> 5) * 2048 + lane * 8;
  const _Float16* Bf1 = Bblk + (long)(c1 >> 7) * 131072 + ((c1 & 127) >> 5) * 2048 + lane * 8;

  const long thrA = (long)(tid >> 7) * 2048 + (tid & 127) * 8;

  // prologue: stage A K-halves 0,1,2; load B(0); drain; read A(0)
#pragma unroll
  for (int g0 = 0; g0 < 3; ++g0) {
    const long go = (long)(g0 >> 1) * 8192 + (long)(g0 & 1) * 1024 + thrA;
    __builtin_amdgcn_global_load_lds(AS1(Ablk + go), AS3(ring + g0 * 4096 + wid * 512), 16, 0, 0);
  }
  half8 a0[2][2], a1[2][2], b0[2][2], b1[2][2];
#pragma unroll
  for (int ks = 0; ks < 2; ++ks) {
    b0[0][ks] = *(const half8*)(Bf0 + ks * 512);
    b0[1][ks] = *(const half8*)(Bf1 + ks * 512);
  }
  asm volatile("s_waitcnt vmcnt(0)" ::: "memory");
  __builtin_amdgcn_s_barrier();
  asm volatile("" ::: "memory");
  {
    const _Float16* sA = ring + lane * 8;
#pragma unroll
    for (int mt = 0; mt < 2; ++mt)
#pragma unroll
      for (int ks = 0; ks < 2; ++ks)
        a0[mt][ks] = *(const half8*)(sA + (((wm >> 5) + mt) * 2 + ks) * 512);
  }

  floatx16 acc[2][2] = {};
#pragma unroll
  for (int pr = 0; pr < 14; ++pr) {
    aft_p<5, true, true, true, true>(2 * pr, Ablk, Bf0, Bf1, ring, thrA, wid, lane, wm,
                                     a0, a1, b0, b1, acc);
    aft_p<5, true, true, true, true>(2 * pr + 1, Ablk, Bf0, Bf1, ring, thrA, wid, lane, wm,
                                     a1, a0, b1, b0, acc);
  }
  aft_p<5, true, true, true, true>(28, Ablk, Bf0, Bf1, ring, thrA, wid, lane, wm,
                                   a0, a1, b0, b1, acc);
  aft_p<4, false, true, true, true>(29, Ablk, Bf0, Bf1, ring, thrA, wid, lane, wm,
                                    a1, a0, b1, b0, acc);
  aft_p<-1, false, true, true, false>(30, Ablk, Bf0, Bf1, ring, thrA, wid, lane, wm,
                                      a0, a1, b0, b1, acc);
  aft_p<-1, false, false, false, false>(31, Ablk, Bf0, Bf1, ring, thrA, wid, lane, wm,
                                        a1, a0, b1, b0, acc);

  if (MODE == 0) {
    if (n0 < 1024) {
      _Float16* Qs = (_Float16*)Cv;
#pragma unroll
      for (int mt = 0; mt < 2; ++mt) {
        const long ttile = (m0 + wm + mt * 32) >> 5;
#pragma unroll
        for (int nt = 0; nt < 2; ++nt) {
          const int col = n0 + wn + nt * 32 + l32;
          const float bb = bias0[col];
          const long base = (ttile * 32 + (((n0 + wn) >> 5) + nt)) * 1024;
#pragma unroll
          for (int q = 0; q < 4; ++q) {
            half4v o;
#pragma unroll
            for (int rr = 0; rr < 4; ++rr) {
              const float v = acc[mt][nt][q * 4 + rr] + bb;
              o[rr] = (_Float16)(1.0f / (1.0f + __expf(-v)));
            }
            *(half4v*)(Qs + base + q * 256 + lane * 4) = o;
          }
        }
      }
    } else {
      const int grp = (n0 - 1024 + wn) >> 6;  // 32-channel group
      const int ch = grp * 32 + l32;
      const float bkc = bias1[ch], bvc = bias2[ch];
      const int jn = grp * 64 + l32;          // Zt num row; den = +32 (same 128-tile)
      const int b = m0 >> 11;
      char* Z8 = Zt8 + (long)b * 4194304 +
                 ((long)(jn >> 7) * 16 + ((m0 & 2047) >> 7)) * 16384;
      const int jnl = jn & 127;
      float sk = 0.f, sz = 0.f;
#pragma unroll
      for (int mt = 0; mt < 2; ++mt) {
#pragma unroll
        for (int q = 0; q < 4; ++q) {
          float ekv[4], ekk[4];
#pragma unroll
          for (int rr = 0; rr < 4; ++rr) {
            const float ek = __expf(acc[mt][0][q * 4 + rr] + bkc);
            const float vv = acc[mt][1][q * 4 + rr] + bvc;
            ekk[rr] = ek;
            ekv[rr] = ek * vv;
            sk += ek;
            sz += ek * vv;
          }
          const int sl = wm + mt * 32 + 4 * khalf + 8 * q;  // s within tile (+rr)
          int pn = __builtin_amdgcn_cvt_pk_fp8_f32(ekv[0] * 0.25f, ekv[1] * 0.25f, 0, false);
          pn = __builtin_amdgcn_cvt_pk_fp8_f32(ekv[2] * 0.25f, ekv[3] * 0.25f, pn, true);
          int pd = __builtin_amdgcn_cvt_pk_fp8_f32(ekk[0] * 0.25f, ekk[1] * 0.25f, 0, false);
          pd = __builtin_amdgcn_cvt_pk_fp8_f32(ekk[2] * 0.25f, ekk[3] * 0.25f, pd, true);
          *(int*)(Z8 + off8(jnl, sl)) = pn;
          *(int*)(Z8 + off8(jnl + 32, sl)) = pd;
        }
      }
      atomicAdd(&cs[(long)b * 2048 + ch * 2], sz);
      atomicAdd(&cs[(long)b * 2048 + ch * 2 + 1], sk);
    }
    return;
  }

  // MODE 2: fp32 row-major + bias0
#pragma unroll
  for (int mt = 0; mt < 2; ++mt)
#pragma unroll
    for (int nt = 0; nt < 2; ++nt) {
      const int col = n0 + wn + nt * 32 + l32;
      const float bb = bias0[col];
#pragma unroll
      for (int reg = 0; reg < 16; ++reg) {
        const int row = m0 + wm + mt * 32 + 4 * khalf + 8 * (reg >> 2) + (reg & 3);
        ((float*)Cv)[(long)row * 1024 + col] = acc[mt][nt][reg] + bb;
      }
    }
}

// ---------------- GEMM2: fp8 correction  acc = (E*32) @ (Z/4)^T ----------------
// N-dim = 2048 (num/den interleaved per 64-group).  Block 256 rows x 256 nd-cols,
// 512 thr / 8 waves (4Mx2N, wave 64x128, acc[2][4]); K=2048 = 32 slices of 64;
// ring-3 LDS: slot = A 16KB (2 strips x 4 chunks of 2048B) + B 16KB; 96KB total.
// Phase g: read slot g%3 -> stage slice g+2 into slot (g+2)%3 (4 loads/thread) ->
// vmcnt(4) -> barrier -> lgkmcnt(0) -> 8 mfma_scale -> barrier.
// OutHead = Qsig * (csZ + accn/8) / (csK + accd/8).  Grid 8m x 8n x 4b = 256, 1/CU.
template <int VM, bool STAGE, int SLOT>
__device__ __forceinline__ void g2_phase(int g, char* __restrict__ ringA, char* __restrict__ ringB,
                                         const char* At0, const char* At1,
                                         const char* Bt0, const char* Bt1,
                                         int tid, int lane, int wm, int wn,
                                         floatx16 (&acc)[2][4]) {
  const int l32 = lane & 31, khalf = lane >> 5;
  intx8 a8[2], b8[4];
#pragma unroll
  for (int mt = 0; mt < 2; ++mt) {
    const int G = (wm >> 5) + mt;  // 0..7 over 256 rows
    const char* pa = ringA + SLOT * 16384 + (G >> 2) * 8192 + (G & 3) * 2048 + khalf * 512 + l32 * 16;
    const intx4 alo = *(const intx4*)pa;
    const intx4 ahi = *(const intx4*)(pa + 1024);
    a8[mt] = __builtin_shufflevector(alo, ahi, 0, 1, 2, 3, 4, 5, 6, 7);
  }
#pragma unroll
  for (int nt = 0; nt < 4; ++nt) {
    const int Gn = (wn >> 5) + nt;  // 0..7 over 256 nd-rows
    const char* pb = ringB + SLOT * 16384 + (Gn >> 2) * 8192 + (Gn & 3) * 2048 + khalf * 512 + l32 * 16;
    const intx4 blo = *(const intx4*)pb;
    const intx4 bhi = *(const intx4*)(pb + 1024);
    b8[nt] = __builtin_shufflevector(blo, bhi, 0, 1, 2, 3, 4, 5, 6, 7);
  }
  if (STAGE) {
    const int ks = g + 2;  // slice 2..31
    constexpr int SS = (SLOT + 2) % 3;
    const long gsrc = (long)(ks >> 1) * 16384 + (long)(tid >> 7) * 4096 + (long)(ks & 1) * 2048 +
                      (tid & 127) * 16;
    char* dA = ringA + SS * 16384 + tid * 16;
    char* dB = ringB + SS * 16384 + tid * 16;
    __builtin_amdgcn_global_load_lds(AS1(At0 + gsrc), AS3(dA), 16, 0, 0);
    __builtin_amdgcn_global_load_lds(AS1(At1 + gsrc), AS3(dA + 8192), 16, 0, 0);
    __builtin_amdgcn_global_load_lds(AS1(Bt0 + gsrc), AS3(dB), 16, 0, 0);
    __builtin_amdgcn_global_load_lds(AS1(Bt1 + gsrc), AS3(dB + 8192), 16, 0, 0);
  }
  if constexpr (VM >= 0) {
    asm volatile("s_waitcnt vmcnt(%0)" ::"i"(VM) : "memory");
    __builtin_amdgcn_s_barrier();
  }
  asm volatile("s_waitcnt lgkmcnt(0)" ::: "memory");
  __builtin_amdgcn_s_setprio(1);
#pragma unroll
  for (int mt = 0; mt < 2; ++mt)
#pragma unroll
    for (int nt = 0; nt < 4; ++nt)
      acc[mt][nt] = __builtin_amdgcn_mfma_scale_f32_32x32x64_f8f6f4(
          a8[mt], b8[nt], acc[mt][nt], 0, 0, 0, 127u, 0, 127u);
  __builtin_amdgcn_s_setprio(0);
  if constexpr (VM >= 0) {
    __builtin_amdgcn_s_barrier();
    asm volatile("" ::: "memory");
  }
}

__global__ __launch_bounds__(512, 1) void gemm2_fp8(
    const char* __restrict__ E8, const char* __restrict__ Zt8, _Float16* __restrict__ OH,
    const _Float16* __restrict__ Qsig, const float* __restrict__ cs) {
  __shared__ __align__(16) char ring[98304];  // A: 3x16KB | B: 3x16KB
  char* ringA = ring;
  char* ringB = ring + 49152;
  const int tid = threadIdx.x;
  const int wid = tid >> 6, lane = tid & 63;
  const int l32 = lane & 31, khalf = lane >> 5;

  const int f = blockIdx.x;
  const int bxs = f & 7;            // m-tile (256 T-rows) -> XCD affinity
  const int bys = (f >> 3) & 7;     // n-tile (256 nd-cols of 2048)
  const int bzs = f >> 6;           // batch
  const int m0 = bxs * 256;
  const int wm = (wid >> 1) * 64, wn = (wid & 1) * 128;

  const char* At0 = E8 + (long)(bxs * 2) * 262144;   // strip = 16 k-tiles * 16384
  const char* At1 = At0 + 262144;
  const char* Bt0 = Zt8 + (long)bzs * 4194304 + (long)(bys * 2) * 262144;
  const char* Bt1 = Bt0 + 262144;

  // prologue: stage slices 0 -> slot 0, 1 -> slot 1 (8 loads); drain oldest 4
#pragma unroll
  for (int ks = 0; ks < 2; ++ks) {
    const long gsrc = (long)(tid >> 7) * 4096 + (long)(ks & 1) * 2048 + (tid & 127) * 16;
    char* dA = ringA + ks * 16384 + tid * 16;
    char* dB = ringB + ks * 16384 + tid * 16;
    __builtin_amdgcn_global_load_lds(AS1(At0 + gsrc), AS3(dA), 16, 0, 0);
    __builtin_amdgcn_global_load_lds(AS1(At1 + gsrc), AS3(dA + 8192), 16, 0, 0);
    __builtin_amdgcn_global_load_lds(AS1(Bt0 + gsrc), AS3(dB), 16, 0, 0);
    __builtin_amdgcn_global_load_lds(AS1(Bt1 + gsrc), AS3(dB + 8192), 16, 0, 0);
  }
  asm volatile("s_waitcnt vmcnt(4)" ::: "memory");
  __builtin_amdgcn_s_barrier();
  asm volatile("" ::: "memory");

  floatx16 acc[2][4] = {};
#pragma unroll 1
  for (int gb = 0; gb < 30; gb += 3) {
    g2_phase<4, true, 0>(gb + 0, ringA, ringB, At0, At1, Bt0, Bt1, tid, lane, wm, wn, acc);
    g2_phase<4, true, 1>(gb + 1, ringA, ringB, At0, At1, Bt0, Bt1, tid, lane, wm, wn, acc);
    g2_phase<4, true, 2>(gb + 2, ringA, ringB, At0, At1, Bt0, Bt1, tid, lane, wm, wn, acc);
  }
  g2_phase<0, false, 0>(30, ringA, ringB, At0, At1, Bt0, Bt1, tid, lane, wm, wn, acc);
  g2_phase<-1, false, 1>(31, ringA, ringB, At0, At1, Bt0, Bt1, tid, lane, wm, wn, acc);

  // epilogue: pairs (2p, 2p+1) = (num, den) of channel (bys*4 + wn/64 + p)*32 + l32
  const int g32b = bys * 4 + (wn >> 6);
#pragma unroll
  for (int mt = 0; mt < 2; ++mt) {
    const long ttile = (long)(bzs * 2048 + m0 + wm + mt * 32) >> 5;
#pragma unroll
    for (int p = 0; p < 2; ++p) {
      const int g32 = g32b + p;
      const int ch = g32 * 32 + l32;
      const float2 c2 = *(const float2*)(cs + (long)bzs * 2048 + ch * 2);  // (csZ, csK)
      const long qbase = (ttile * 32 + g32) * 1024;
#pragma unroll
      for (int q = 0; q < 4; ++q) {
        const half4v qv = *(const half4v*)(Qsig + qbase + q * 256 + lane * 4);
#pragma unroll
        for (int rr = 0; rr < 4; ++rr) {
          const int reg = q * 4 + rr;
          const float num = c2.x + acc[mt][2 * p][reg] * 0.125f;
          const float den = c2.y + acc[mt][2 * p + 1][reg] * 0.125f;
          const int r = m0 + wm + mt * 32 + 4 * khalf + 8 * q + rr;
          const int R = bzs * 2048 + r;
          const long off = ((long)(R >> 7) * 16 + (ch >> 6)) * 8192 + frag_off(R & 127, ch & 63);
          OH[off] = (_Float16)((float)qv[rr] * num / den);
        }
      }
    }
  }
}

// ---------------- launch ----------------
extern "C" void kernel_launch(void* const* d_in, const int* in_sizes, int n_in, void* d_out,
                              int out_size, void* d_ws, size_t ws_size, hipStream_t stream) {
  const float* x = (const float*)d_in[0];
  const float* Wq = (const float*)d_in[1];
  const float* bq = (const float*)d_in[2];
  const float* Wk = (const float*)d_in[3];
  const float* bk = (const float*)d_in[4];
  const float* Wv = (const float*)d_in[5];
  const float* bv = (const float*)d_in[6];
  const float* Wo = (const float*)d_in[7];
  const float* bo = (const float*)d_in[8];
  const float* wb = (const float*)d_in[9];

  char* ws = (char*)d_ws;
  _Float16* x_h = (_Float16*)(ws + 0);              // 16 MB  (1024 f16 frag tiles)
  _Float16* WqkvT = (_Float16*)(ws + 16777216);     //  6 MB
  _Float16* WoT = (_Float16*)(ws + 23068672);       //  2 MB
  char* E8 = (char*)(ws + 25165824);                //  4 MB  (256 fp8 frag tiles)
  _Float16* Qsig = (_Float16*)(ws + 29360128);      // 16 MB  (C-frag tiles)
  char* Zt8 = (char*)(ws + 46137344);               // 16 MB  (fp8 frag tiles, 4 batches)
  _Float16* OutHead = (_Float16*)(ws + 62914560);   // 16 MB  (f16 frag tiles)
  float* cs = (float*)(ws + 79691776);              // 32 KB  (csZ,csK interleaved)

  hipMemsetAsync(cs, 0, 4 * 2048 * sizeof(float), stream);

  // prep: x tiles + weight tiles + E8 tiles
  prep_all<<<1792, 256, 0, stream>>>(x, wb, Wq, Wk, Wv, Wo, x_h, E8, WqkvT, WoT);

  // GEMM1: x @ [Wq|Wkv]; epilogue -> Qsig (C-frag), Zt8 (fp8), colsum atomics
  gemm_bt2<0><<<768, 512, 0, stream>>>(x_h, WqkvT, Qsig, bq, bk, bv, Zt8, cs);

  // GEMM2 (fp8 correction + rank-1): OutHead = Qsig*(csZ+E@Z)/(csK+E@eK)
  gemm2_fp8<<<256, 512, 0, stream>>>(E8, Zt8, OutHead, Qsig, cs);

  // GEMM3: out = OutHead @ Wo + bo (fp32)
  gemm_bt2<2><<<256, 512, 0, stream>>>(OutHead, WoT, d_out, bo, nullptr, nullptr, nullptr, nullptr);
}

// Round 9
// 245.916 us; speedup vs baseline: 1.0308x; 1.0308x over previous
//
#include <hip/hip_runtime.h>
#include <hip/hip_bf16.h>

// AFT-Full on gfx950 — fragment-linear + MX-fp8 GEMM2 + XCD-slab scheduling.
// ew = exp(wbias) = 1 + E, |E|<=0.039: num = colsumZ + E@eKV, den = colsumK + E@eK.
// colsums exact (f32 atomics in GEMM1 epilogue); correction GEMM in fp8 e4m3 via
// mfma_scale_f32_32x32x64_f8f6f4 (scales pinned 1.0; static E*32, Z/4, /8 undo).
// Round-17: base = round-15 (best: GEMM1 67.5us fine-interleave BK=64 ring-3).
// Changes: (1) GEMM2 drops its explicit lgkmcnt(0) drain between the 12 ds_reads
// and the 8 mfma_scale — compiler emits counted partial lgkm waits instead, so
// the MFMA cluster overlaps the read-burst tail (WAR stays guarded by barrier-2);
// reads reordered (a8[0], b8[0..1], a8[1], b8[2..3]) to match consumption order.
// (2) cs-zeroing folded into prep_all block 1792 (kills the hipMemsetAsync
// dispatch; stream order still gives cs=0 before GEMM1's atomics).
// Round-16 lesson (B direct-to-reg, -10us): per-reg vmcnt on global B loads
// couples L2 latency into the MFMA stream — keep both operands LDS-staged.

#define AS1(p) ((const __attribute__((address_space(1))) void*)(p))
#define AS3(p) ((__attribute__((address_space(3))) void*)(p))

typedef _Float16 half8 __attribute__((ext_vector_type(8)));
typedef _Float16 half4v __attribute__((ext_vector_type(4)));
typedef float floatx16 __attribute__((ext_vector_type(16)));
typedef int intx4 __attribute__((ext_vector_type(4)));
typedef int intx8 __attribute__((ext_vector_type(8)));

// f16 fragment-linear 128x64 tile (8192 halfs): [r>>5][k>>4][(k>>3)&1][r&31][k&7]
__device__ __forceinline__ long frag_off(int r, int k) {
  return (long)(((((r >> 5) * 4 + (k >> 4)) * 2 + ((k >> 3) & 1)) * 32 + (r & 31)) * 8 + (k & 7));
}
// fp8 fragment-linear 128x128 tile (16384 B)
__device__ __forceinline__ long off8(int r, int k) {
  return (long)((((((r >> 5) * 2 + ((k >> 6) & 1)) * 2 + ((k >> 4) & 1)) * 2 + ((k >> 5) & 1)) * 32 +
                 (r & 31)) * 16 + (k & 15));
}

// ---------------- prep_all ----------------
// blocks [0,1024): x -> f16 frag tiles; [1024,1536): W -> f16 tiles via LDS;
// [1536,1792): (exp(wbias)-1)*32 -> fp8 frag tiles; block 1792: zero cs.
__global__ __launch_bounds__(256) void prep_all(
    const float* __restrict__ x, const float* __restrict__ wb, const float* __restrict__ Wq,
    const float* __restrict__ Wk, const float* __restrict__ Wv, const float* __restrict__ Wo,
    _Float16* __restrict__ x_h, char* __restrict__ E8, _Float16* __restrict__ WqkvT,
    _Float16* __restrict__ WoT, float* __restrict__ cs) {
  __shared__ _Float16 lds[64 * 132];
  const int bid = blockIdx.x;
  const int tid = threadIdx.x;

  if (bid >= 1792) {  // zero colsum accumulators (8192 floats = 32 KB)
    float4 z = {0.f, 0.f, 0.f, 0.f};
#pragma unroll
    for (int p = 0; p < 8; ++p) *(float4*)(cs + (p * 256 + tid) * 4) = z;
    return;
  }

  if (bid < 1024) {  // x -> f16 tiles
    const int tm = bid >> 4, tk = bid & 15;
    const long tbase = (long)bid * 8192;
#pragma unroll
    for (int p = 0; p < 4; ++p) {
      const int s = p * 256 + tid;
      const int r = ((s >> 8) << 5) + (s & 31);
      const int k = ((s >> 6) & 3) * 16 + ((s >> 5) & 1) * 8;
      const float* sp = x + (long)(tm * 128 + r) * 1024 + tk * 64 + k;
      const float4 v0 = *(const float4*)sp;
      const float4 v1 = *(const float4*)(sp + 4);
      half8 h;
      h[0] = (_Float16)v0.x; h[1] = (_Float16)v0.y; h[2] = (_Float16)v0.z; h[3] = (_Float16)v0.w;
      h[4] = (_Float16)v1.x; h[5] = (_Float16)v1.y; h[6] = (_Float16)v1.z; h[7] = (_Float16)v1.w;
      *(half8*)(x_h + tbase + (long)s * 8) = h;
    }
    return;
  }

  if (bid >= 1536) {  // E8: (exp(wb)-1)*32 -> fp8 frag tiles
    const int e = bid - 1536;
    const int tt = e >> 4, ts = e & 15;
    char* dst = E8 + (long)e * 16384;
#pragma unroll
    for (int p = 0; p < 16; ++p) {
      const int idx = p * 256 + tid;
      const int r = idx >> 5, k = (idx & 31) * 4;
      const float4 v = *(const float4*)(wb + (long)(tt * 128 + r) * 2048 + ts * 128 + k);
      const float e0 = (__expf(v.x) - 1.0f) * 32.0f, e1 = (__expf(v.y) - 1.0f) * 32.0f;
      const float e2 = (__expf(v.z) - 1.0f) * 32.0f, e3 = (__expf(v.w) - 1.0f) * 32.0f;
      int pk = __builtin_amdgcn_cvt_pk_fp8_f32(e0, e1, 0, false);
      pk = __builtin_amdgcn_cvt_pk_fp8_f32(e2, e3, pk, true);
      *(int*)(dst + off8(r, k)) = pk;
    }
    return;
  }

  // ---- weight tiler (f16) ----
  const int b2 = bid - 1024;
  const float* src0;
  const float* src1 = nullptr;
  _Float16* dst;
  int tn, tk, cb = 0;
  if (b2 < 128) {
    tn = b2 >> 4; tk = b2 & 15; src0 = Wq; dst = WqkvT;
  } else if (b2 < 384) {
    const int t = b2 - 128;
    tn = 8 + (t >> 4); tk = t & 15; cb = (tn - 8) * 64; src0 = Wk; src1 = Wv; dst = WqkvT;
  } else {
    const int t = b2 - 384;
    tn = t >> 4; tk = t & 15; src0 = Wo; dst = WoT;
  }
  if (!src1) {
#pragma unroll
    for (int p = 0; p < 8; ++p) {
      const int kl = p * 8 + (tid >> 5);
      const int cl = (tid & 31) * 4;
      const float4 v = *(const float4*)(src0 + (long)(tk * 64 + kl) * 1024 + tn * 128 + cl);
      half4v h;
      h[0] = (_Float16)v.x; h[1] = (_Float16)v.y; h[2] = (_Float16)v.z; h[3] = (_Float16)v.w;
      *(half4v*)(lds + kl * 132 + cl) = h;
    }
  } else {
#pragma unroll
    for (int m = 0; m < 2; ++m) {
      const float* s = m ? src1 : src0;
      const int rb = m ? 32 : 0;
#pragma unroll
      for (int p = 0; p < 4; ++p) {
        const int kl = p * 16 + (tid >> 4);
        const int cl = (tid & 15) * 4;
        const int rl = (cl >> 5) * 64 + rb + (cl & 31);
        const float4 v = *(const float4*)(s + (long)(tk * 64 + kl) * 1024 + cb + cl);
        half4v h;
        h[0] = (_Float16)v.x; h[1] = (_Float16)v.y; h[2] = (_Float16)v.z; h[3] = (_Float16)v.w;
        *(half4v*)(lds + kl * 132 + rl) = h;
      }
    }
  }
  __syncthreads();
  const long tbase = (long)(tn * 16 + tk) * 8192;
#pragma unroll
  for (int p = 0; p < 4; ++p) {
    const int s = p * 256 + tid;
    const int r = ((s >> 8) << 5) + (s & 31);
    const int kl = ((s >> 6) & 3) * 16 + ((s >> 5) & 1) * 8;
    half8 h;
#pragma unroll
    for (int j = 0; j < 8; ++j) h[j] = lds[(kl + j) * 132 + r];
    *(half8*)(dst + tbase + (long)s * 8) = h;
  }
}

// ---------------- f16 GEMM: 128x256, 8 waves, BK=64 ring-3, fine alternation ----------------
template <int KS>
__device__ __forceinline__ void rd_ab(const _Float16* sA, const _Float16* sB, int wm, int wn,
                                      int lane, half8 (&a)[2], half8 (&b)[2]) {
  a[0] = *(const half8*)(sA + (((wm >> 5) + 0) * 4 + KS) * 512 + lane * 8);
  a[1] = *(const half8*)(sA + (((wm >> 5) + 1) * 4 + KS) * 512 + lane * 8);
  b[0] = *(const half8*)(sB + (((wn >> 5) + 0) * 4 + KS) * 512 + lane * 8);
  b[1] = *(const half8*)(sB + (((wn >> 5) + 1) * 4 + KS) * 512 + lane * 8);
}

__device__ __forceinline__ void mm4(const half8 (&a)[2], const half8 (&b)[2],
                                    floatx16 (&acc)[2][2]) {
  __builtin_amdgcn_s_setprio(1);
#pragma unroll
  for (int mt = 0; mt < 2; ++mt)
#pragma unroll
    for (int nt = 0; nt < 2; ++nt)
      acc[mt][nt] = __builtin_amdgcn_mfma_f32_32x32x16_f16(a[mt], b[nt], acc[mt][nt], 0, 0, 0);
  __builtin_amdgcn_s_setprio(0);
}

// Per tile t: stage(t+2); {rd ks1||mm ks0}{rd ks2||mm ks1}{rd ks3||mm ks2};
// vmcnt(VM); barrier; {rd (t+1,ks0)||mm ks3}.
template <int VM, bool STAGE, bool LAST>
__device__ __forceinline__ void tile_step(int t, const _Float16* __restrict__ Ablk,
                                          const _Float16* __restrict__ Bblk, _Float16* ring,
                                          int tid, int lane, int wm, int wn,
                                          half8 (&a0)[2], half8 (&b0)[2], half8 (&a1)[2],
                                          half8 (&b1)[2], floatx16 (&acc)[2][2]) {
  const _Float16* sA = ring + (t % 3) * 8192;
  const _Float16* sB = ring + 24576 + (t % 3) * 16384;
  if (STAGE) {
    const int ts = t + 2;
    _Float16* dA = ring + (ts % 3) * 8192 + tid * 8;
    _Float16* dB = ring + 24576 + (ts % 3) * 16384 + tid * 8;
    const _Float16* gA = Ablk + (long)ts * 8192 + tid * 8;
    const _Float16* gB = Bblk + (long)ts * 8192 + tid * 8;
    __builtin_amdgcn_global_load_lds(AS1(gA), AS3(dA), 16, 0, 0);
    __builtin_amdgcn_global_load_lds(AS1(gA + 4096), AS3(dA + 4096), 16, 0, 0);
    __builtin_amdgcn_global_load_lds(AS1(gB), AS3(dB), 16, 0, 0);
    __builtin_amdgcn_global_load_lds(AS1(gB + 4096), AS3(dB + 4096), 16, 0, 0);
    __builtin_amdgcn_global_load_lds(AS1(gB + 131072), AS3(dB + 8192), 16, 0, 0);
    __builtin_amdgcn_global_load_lds(AS1(gB + 131072 + 4096), AS3(dB + 12288), 16, 0, 0);
  }
  rd_ab<1>(sA, sB, wm, wn, lane, a1, b1);
  mm4(a0, b0, acc);
  rd_ab<2>(sA, sB, wm, wn, lane, a0, b0);
  mm4(a1, b1, acc);
  rd_ab<3>(sA, sB, wm, wn, lane, a1, b1);
  mm4(a0, b0, acc);
  if (!LAST) {
    asm volatile("s_waitcnt vmcnt(%0)" ::"i"(VM < 0 ? 0 : VM) : "memory");
    __builtin_amdgcn_s_barrier();
    asm volatile("" ::: "memory");
    const _Float16* nA = ring + ((t + 1) % 3) * 8192;
    const _Float16* nB = ring + 24576 + ((t + 1) % 3) * 16384;
    rd_ab<0>(nA, nB, wm, wn, lane, a0, b0);
  }
  mm4(a1, b1, acc);
}

// Block order: XCD x = f&7 owns m-slab [8x, 8x+8) of 128-row tiles, walks n slowly.
// MODE 0 (GEMM1): n0<1024 -> Qsig C-frag sigmoid(+bq); else K/V pair -> Zt8 + colsums.
// MODE 2 (GEMM3): fp32 row-major store + bias0.
template <int MODE>
__global__ __launch_bounds__(512, 1) void gemm_bt2(
    const _Float16* __restrict__ A, const _Float16* __restrict__ Bt, void* __restrict__ Cv,
    const float* __restrict__ bias0, const float* __restrict__ bias1,
    const float* __restrict__ bias2, char* __restrict__ Zt8, float* __restrict__ cs) {
  __shared__ __align__(16) _Float16 ring[73728];  // A: 3x8192 | B: 3x16384 halfs (144 KB)
  const int tid = threadIdx.x;
  const int wid = tid >> 6, lane = tid & 63;
  const int l32 = lane & 31, khalf = lane >> 5;

  const int f = blockIdx.x;
  const int j = f >> 3;
  const int bxs = (f & 7) * 8 + (j & 7);
  const int bys = j >> 3;
  const int m0 = bxs * 128, n0 = bys * 256;
  const int wm = (wid >> 2) * 64, wn = (wid & 3) * 64;

  const _Float16* Ablk = A + (long)bxs * 131072;          // 16 tiles * 8192
  const _Float16* Bblk = Bt + (long)(bys * 2) * 131072;   // 2 consecutive 128-col tiles

  // prologue: stage tiles 0,1 (12 loads); drain oldest 6 -> tile 0 ready
#pragma unroll
  for (int t0 = 0; t0 < 2; ++t0) {
    _Float16* dA = ring + t0 * 8192 + tid * 8;
    _Float16* dB = ring + 24576 + t0 * 16384 + tid * 8;
    const _Float16* gA = Ablk + (long)t0 * 8192 + tid * 8;
    const _Float16* gB = Bblk + (long)t0 * 8192 + tid * 8;
    __builtin_amdgcn_global_load_lds(AS1(gA), AS3(dA), 16, 0, 0);
    __builtin_amdgcn_global_load_lds(AS1(gA + 4096), AS3(dA + 4096), 16, 0, 0);
    __builtin_amdgcn_global_load_lds(AS1(gB), AS3(dB), 16, 0, 0);
    __builtin_amdgcn_global_load_lds(AS1(gB + 4096), AS3(dB + 4096), 16, 0, 0);
    __builtin_amdgcn_global_load_lds(AS1(gB + 131072), AS3(dB + 8192), 16, 0, 0);
    __builtin_amdgcn_global_load_lds(AS1(gB + 131072 + 4096), AS3(dB + 12288), 16, 0, 0);
  }
  asm volatile("s_waitcnt vmcnt(6)" ::: "memory");
  __builtin_amdgcn_s_barrier();
  asm volatile("" ::: "memory");

  half8 a0[2], b0[2], a1[2], b1[2];
  rd_ab<0>(ring, ring + 24576, wm, wn, lane, a0, b0);

  floatx16 acc[2][2] = {};
#pragma unroll
  for (int t = 0; t < 14; ++t)
    tile_step<6, true, false>(t, Ablk, Bblk, ring, tid, lane, wm, wn, a0, b0, a1, b1, acc);
  tile_step<0, false, false>(14, Ablk, Bblk, ring, tid, lane, wm, wn, a0, b0, a1, b1, acc);
  tile_step<0, false, true>(15, Ablk, Bblk, ring, tid, lane, wm, wn, a0, b0, a1, b1, acc);

  if (MODE == 0) {
    if (n0 < 1024) {
      _Float16* Qs = (_Float16*)Cv;
#pragma unroll
      for (int mt = 0; mt < 2; ++mt) {
        const long ttile = (m0 + wm + mt * 32) >> 5;
#pragma unroll
        for (int nt = 0; nt < 2; ++nt) {
          const int col = n0 + wn + nt * 32 + l32;
          const float bb = bias0[col];
          const long base = (ttile * 32 + (((n0 + wn) >> 5) + nt)) * 1024;
#pragma unroll
          for (int q = 0; q < 4; ++q) {
            half4v o;
#pragma unroll
            for (int rr = 0; rr < 4; ++rr) {
              const float v = acc[mt][nt][q * 4 + rr] + bb;
              o[rr] = (_Float16)(1.0f / (1.0f + __expf(-v)));
            }
            *(half4v*)(Qs + base + q * 256 + lane * 4) = o;
          }
        }
      }
    } else {
      const int grp = (n0 - 1024 + wn) >> 6;  // 32-channel group
      const int ch = grp * 32 + l32;
      const float bkc = bias1[ch], bvc = bias2[ch];
      const int jn = grp * 64 + l32;          // Zt num row; den = +32 (same 128-tile)
      const int b = m0 >> 11;
      char* Z8 = Zt8 + (long)b * 4194304 +
                 ((long)(jn >> 7) * 16 + ((m0 & 2047) >> 7)) * 16384;
      const int jnl = jn & 127;
      float sk = 0.f, sz = 0.f;
#pragma unroll
      for (int mt = 0; mt < 2; ++mt) {
#pragma unroll
        for (int q = 0; q < 4; ++q) {
          float ekv[4], ekk[4];
#pragma unroll
          for (int rr = 0; rr < 4; ++rr) {
            const float ek = __expf(acc[mt][0][q * 4 + rr] + bkc);
            const float vv = acc[mt][1][q * 4 + rr] + bvc;
            ekk[rr] = ek;
            ekv[rr] = ek * vv;
            sk += ek;
            sz += ek * vv;
          }
          const int sl = wm + mt * 32 + 4 * khalf + 8 * q;  // s within tile (+rr)
          int pn = __builtin_amdgcn_cvt_pk_fp8_f32(ekv[0] * 0.25f, ekv[1] * 0.25f, 0, false);
          pn = __builtin_amdgcn_cvt_pk_fp8_f32(ekv[2] * 0.25f, ekv[3] * 0.25f, pn, true);
          int pd = __builtin_amdgcn_cvt_pk_fp8_f32(ekk[0] * 0.25f, ekk[1] * 0.25f, 0, false);
          pd = __builtin_amdgcn_cvt_pk_fp8_f32(ekk[2] * 0.25f, ekk[3] * 0.25f, pd, true);
          *(int*)(Z8 + off8(jnl, sl)) = pn;
          *(int*)(Z8 + off8(jnl + 32, sl)) = pd;
        }
      }
      atomicAdd(&cs[(long)b * 2048 + ch * 2], sz);
      atomicAdd(&cs[(long)b * 2048 + ch * 2 + 1], sk);
    }
    return;
  }

  // MODE 2: fp32 row-major + bias0
#pragma unroll
  for (int mt = 0; mt < 2; ++mt)
#pragma unroll
    for (int nt = 0; nt < 2; ++nt) {
      const int col = n0 + wn + nt * 32 + l32;
      const float bb = bias0[col];
#pragma unroll
      for (int reg = 0; reg < 16; ++reg) {
        const int row = m0 + wm + mt * 32 + 4 * khalf + 8 * (reg >> 2) + (reg & 3);
        ((float*)Cv)[(long)row * 1024 + col] = acc[mt][nt][reg] + bb;
      }
    }
}

// ---------------- GEMM2: fp8 correction  acc = (E*32) @ (Z/4)^T ----------------
// N-dim = 2048 (num/den interleaved per 64-group).  Block 256 rows x 256 nd-cols,
// 512 thr / 8 waves (4Mx2N, wave 64x128, acc[2][4]); K=2048 = 32 slices of 64;
// ring-3 LDS: slot = A 16KB (2 strips x 4 chunks of 2048B) + B 16KB; 96KB total.
// Phase g: reads (a8[0], b8[0..1], a8[1], b8[2..3]) -> stage slice g+2 into slot
// (g+2)%3 -> vmcnt(4) -> barrier -> 8 mfma_scale (compiler counted-lgkm, NO
// explicit lgkmcnt(0) drain: MFMA cluster overlaps read tail) -> barrier (WAR).
// OutHead = Qsig * (csZ + accn/8) / (csK + accd/8).  Grid 8m x 8n x 4b = 256, 1/CU.
template <int VM, bool STAGE, int SLOT>
__device__ __forceinline__ void g2_phase(int g, char* __restrict__ ringA, char* __restrict__ ringB,
                                         const char* At0, const char* At1,
                                         const char* Bt0, const char* Bt1,
                                         int tid, int lane, int wm, int wn,
                                         floatx16 (&acc)[2][4]) {
  const int l32 = lane & 31, khalf = lane >> 5;
  intx8 a8[2], b8[4];
  {
    const int G = (wm >> 5);
    const char* pa = ringA + SLOT * 16384 + (G >> 2) * 8192 + (G & 3) * 2048 + khalf * 512 + l32 * 16;
    const intx4 alo = *(const intx4*)pa;
    const intx4 ahi = *(const intx4*)(pa + 1024);
    a8[0] = __builtin_shufflevector(alo, ahi, 0, 1, 2, 3, 4, 5, 6, 7);
  }
#pragma unroll
  for (int nt = 0; nt < 2; ++nt) {
    const int Gn = (wn >> 5) + nt;
    const char* pb = ringB + SLOT * 16384 + (Gn >> 2) * 8192 + (Gn & 3) * 2048 + khalf * 512 + l32 * 16;
    const intx4 blo = *(const intx4*)pb;
    const intx4 bhi = *(const intx4*)(pb + 1024);
    b8[nt] = __builtin_shufflevector(blo, bhi, 0, 1, 2, 3, 4, 5, 6, 7);
  }
  {
    const int G = (wm >> 5) + 1;
    const char* pa = ringA + SLOT * 16384 + (G >> 2) * 8192 + (G & 3) * 2048 + khalf * 512 + l32 * 16;
    const intx4 alo = *(const intx4*)pa;
    const intx4 ahi = *(const intx4*)(pa + 1024);
    a8[1] = __builtin_shufflevector(alo, ahi, 0, 1, 2, 3, 4, 5, 6, 7);
  }
#pragma unroll
  for (int nt = 2; nt < 4; ++nt) {
    const int Gn = (wn >> 5) + nt;
    const char* pb = ringB + SLOT * 16384 + (Gn >> 2) * 8192 + (Gn & 3) * 2048 + khalf * 512 + l32 * 16;
    const intx4 blo = *(const intx4*)pb;
    const intx4 bhi = *(const intx4*)(pb + 1024);
    b8[nt] = __builtin_shufflevector(blo, bhi, 0, 1, 2, 3, 4, 5, 6, 7);
  }
  if (STAGE) {
    const int ks = g + 2;  // slice 2..31
    constexpr int SS = (SLOT + 2) % 3;
    const long gsrc = (long)(ks >> 1) * 16384 + (long)(tid >> 7) * 4096 + (long)(ks & 1) * 2048 +
                      (tid & 127) * 16;
    char* dA = ringA + SS * 16384 + tid * 16;
    char* dB = ringB + SS * 16384 + tid * 16;
    __builtin_amdgcn_global_load_lds(AS1(At0 + gsrc), AS3(dA), 16, 0, 0);
    __builtin_amdgcn_global_load_lds(AS1(At1 + gsrc), AS3(dA + 8192), 16, 0, 0);
    __builtin_amdgcn_global_load_lds(AS1(Bt0 + gsrc), AS3(dB), 16, 0, 0);
    __builtin_amdgcn_global_load_lds(AS1(Bt1 + gsrc), AS3(dB + 8192), 16, 0, 0);
  }
  if constexpr (VM >= 0) {
    asm volatile("s_waitcnt vmcnt(%0)" ::"i"(VM) : "memory");
    __builtin_amdgcn_s_barrier();
  }
  __builtin_amdgcn_s_setprio(1);
#pragma unroll
  for (int nt = 0; nt < 4; ++nt)
#pragma unroll
    for (int mt = 0; mt < 2; ++mt)
      acc[mt][nt] = __builtin_amdgcn_mfma_scale_f32_32x32x64_f8f6f4(
          a8[mt], b8[nt], acc[mt][nt], 0, 0, 0, 127u, 0, 127u);
  __builtin_amdgcn_s_setprio(0);
  if constexpr (VM >= 0) {
    __builtin_amdgcn_s_barrier();
    asm volatile("" ::: "memory");
  }
}

__global__ __launch_bounds__(512, 1) void gemm2_fp8(
    const char* __restrict__ E8, const char* __restrict__ Zt8, _Float16* __restrict__ OH,
    const _Float16* __restrict__ Qsig, const float* __restrict__ cs) {
  __shared__ __align__(16) char ring[98304];  // A: 3x16KB | B: 3x16KB
  char* ringA = ring;
  char* ringB = ring + 49152;
  const int tid = threadIdx.x;
  const int wid = tid >> 6, lane = tid & 63;
  const int l32 = lane & 31, khalf = lane >> 5;

  const int f = blockIdx.x;
  const int bxs = f & 7;            // m-tile (256 T-rows) -> XCD affinity
  const int bys = (f >> 3) & 7;     // n-tile (256 nd-cols of 2048)
  const int bzs = f >> 6;           // batch
  const int m0 = bxs * 256;
  const int wm = (wid >> 1) * 64, wn = (wid & 1) * 128;

  const char* At0 = E8 + (long)(bxs * 2) * 262144;   // strip = 16 k-tiles * 16384
  const char* At1 = At0 + 262144;
  const char* Bt0 = Zt8 + (long)bzs * 4194304 + (long)(bys * 2) * 262144;
  const char* Bt1 = Bt0 + 262144;

  // prologue: stage slices 0 -> slot 0, 1 -> slot 1 (8 loads); drain oldest 4
#pragma unroll
  for (int ks = 0; ks < 2; ++ks) {
    const long gsrc = (long)(tid >> 7) * 4096 + (long)(ks & 1) * 2048 + (tid & 127) * 16;
    char* dA = ringA + ks * 16384 + tid * 16;
    char* dB = ringB + ks * 16384 + tid * 16;
    __builtin_amdgcn_global_load_lds(AS1(At0 + gsrc), AS3(dA), 16, 0, 0);
    __builtin_amdgcn_global_load_lds(AS1(At1 + gsrc), AS3(dA + 8192), 16, 0, 0);
    __builtin_amdgcn_global_load_lds(AS1(Bt0 + gsrc), AS3(dB), 16, 0, 0);
    __builtin_amdgcn_global_load_lds(AS1(Bt1 + gsrc), AS3(dB + 8192), 16, 0, 0);
  }
  asm volatile("s_waitcnt vmcnt(4)" ::: "memory");
  __builtin_amdgcn_s_barrier();
  asm volatile("" ::: "memory");

  floatx16 acc[2][4] = {};
#pragma unroll 1
  for (int gb = 0; gb < 30; gb += 3) {
    g2_phase<4, true, 0>(gb + 0, ringA, ringB, At0, At1, Bt0, Bt1, tid, lane, wm, wn, acc);
    g2_phase<4, true, 1>(gb + 1, ringA, ringB, At0, At1, Bt0, Bt1, tid, lane, wm, wn, acc);
    g2_phase<4, true, 2>(gb + 2, ringA, ringB, At0, At1, Bt0, Bt1, tid, lane, wm, wn, acc);
  }
  g2_phase<0, false, 0>(30, ringA, ringB, At0, At1, Bt0, Bt1, tid, lane, wm, wn, acc);
  g2_phase<-1, false, 1>(31, ringA, ringB, At0, At1, Bt0, Bt1, tid, lane, wm, wn, acc);

  // epilogue: pairs (2p, 2p+1) = (num, den) of channel (bys*4 + wn/64 + p)*32 + l32
  const int g32b = bys * 4 + (wn >> 6);
#pragma unroll
  for (int mt = 0; mt < 2; ++mt) {
    const long ttile = (long)(bzs * 2048 + m0 + wm + mt * 32) >> 5;
#pragma unroll
    for (int p = 0; p < 2; ++p) {
      const int g32 = g32b + p;
      const int ch = g32 * 32 + l32;
      const float2 c2 = *(const float2*)(cs + (long)bzs * 2048 + ch * 2);  // (csZ, csK)
      const long qbase = (ttile * 32 + g32) * 1024;
#pragma unroll
      for (int q = 0; q < 4; ++q) {
        const half4v qv = *(const half4v*)(Qsig + qbase + q * 256 + lane * 4);
#pragma unroll
        for (int rr = 0; rr < 4; ++rr) {
          const int reg = q * 4 + rr;
          const float num = c2.x + acc[mt][2 * p][reg] * 0.125f;
          const float den = c2.y + acc[mt][2 * p + 1][reg] * 0.125f;
          const int r = m0 + wm + mt * 32 + 4 * khalf + 8 * q + rr;
          const int R = bzs * 2048 + r;
          const long off = ((long)(R >> 7) * 16 + (ch >> 6)) * 8192 + frag_off(R & 127, ch & 63);
          OH[off] = (_Float16)((float)qv[rr] * num / den);
        }
      }
    }
  }
}

// ---------------- launch ----------------
extern "C" void kernel_launch(void* const* d_in, const int* in_sizes, int n_in, void* d_out,
                              int out_size, void* d_ws, size_t ws_size, hipStream_t stream) {
  const float* x = (const float*)d_in[0];
  const float* Wq = (const float*)d_in[1];
  const float* bq = (const float*)d_in[2];
  const float* Wk = (const float*)d_in[3];
  const float* bk = (const float*)d_in[4];
  const float* Wv = (const float*)d_in[5];
  const float* bv = (const float*)d_in[6];
  const float* Wo = (const float*)d_in[7];
  const float* bo = (const float*)d_in[8];
  const float* wb = (const float*)d_in[9];

  char* ws = (char*)d_ws;
  _Float16* x_h = (_Float16*)(ws + 0);              // 16 MB  (1024 f16 frag tiles)
  _Float16* WqkvT = (_Float16*)(ws + 16777216);     //  6 MB
  _Float16* WoT = (_Float16*)(ws + 23068672);       //  2 MB
  char* E8 = (char*)(ws + 25165824);                //  4 MB  (256 fp8 frag tiles)
  _Float16* Qsig = (_Float16*)(ws + 29360128);      // 16 MB  (C-frag tiles)
  char* Zt8 = (char*)(ws + 46137344);               // 16 MB  (fp8 frag tiles, 4 batches)
  _Float16* OutHead = (_Float16*)(ws + 62914560);   // 16 MB  (f16 frag tiles)
  float* cs = (float*)(ws + 79691776);              // 32 KB  (csZ,csK interleaved)

  // prep: x tiles + weight tiles + E8 tiles + cs zeroing (block 1792)
  prep_all<<<1793, 256, 0, stream>>>(x, wb, Wq, Wk, Wv, Wo, x_h, E8, WqkvT, WoT, cs);

  // GEMM1: x @ [Wq|Wkv]; epilogue -> Qsig (C-frag), Zt8 (fp8), colsum atomics
  gemm_bt2<0><<<768, 512, 0, stream>>>(x_h, WqkvT, Qsig, bq, bk, bv, Zt8, cs);

  // GEMM2 (fp8 correction + rank-1): OutHead = Qsig*(csZ+E@Z)/(csK+E@eK)
  gemm2_fp8<<<256, 512, 0, stream>>>(E8, Zt8, OutHead, Qsig, cs);

  // GEMM3: out = OutHead @ Wo + bo (fp32)
  gemm_bt2<2><<<256, 512, 0, stream>>>(OutHead, WoT, d_out, bo, nullptr, nullptr, nullptr, nullptr);
}